// Round 19
// baseline (176.992 us; speedup 1.0000x reference)
//
#include <hip/hip_runtime.h>
#include <hip/hip_bf16.h>
#include <math.h>

// Problem constants (B,L,H,D fixed by setup_inputs; S == L)
#define B_   4
#define L_   2048
#define H_   8
#define D_   64
#define NTOP 38          // int(5*ln(2048)) = 38
#define SAMPK 38

// Verified RNG (r10 PASS): JAX partitionable threefry WITH randint key-split.
// r5 lesson: NO per-block fence/atomic producer-consumer (~170us cost).
// r9 lesson: 16-lane-cooperative gathers are the coalescing backbone (a group
//   must cover one full contiguous K row).
// r11 lesson: grid.sync/cooperative launch incompatible with this harness.
// r15/r16 (PASS): block-parallel radix topk + parallel bucket select.
// r19 (PASS, 167.9us BEST): V staged into sK after P2 (sK dead) -> P3 V-reads
//   from LDS. attn now <48us; m_cumsum (50us) is the top dispatch.
// r20: m dot via 4-lane subgroups: 4x float4/lane keeps the 256B/row coalesced
//   gather; butterfly 4 steps -> 2 (+4-op subgroup combine). DS ops 152->24/thr.
//   smv order changes by ulps (max is exact); selection robust at that scale.

// ---- d_ws layouts ----
#define WS_M_OFF    0                        // float  M[65536]     = 262144 B
#define WS_MTOP_OFF 262144                   // int    mtop[32*38]  =   4864 B
#define WS_SMALL    (WS_MTOP_OFF + 4864)     // 267008 B
// 16-chunk layout (5.4 MB, r3/r4-verified fit) — primary path:
#define NSLOT16     (B_ * H_ * NTOP * 16)    // 19456
#define WS16_PMAX   WS_SMALL
#define WS16_PSUM   (WS16_PMAX + NSLOT16 * 4)
#define WS16_PPV    (WS16_PSUM + NSLOT16 * 4)
#define WS16_TOTAL  (WS16_PPV + NSLOT16 * D_ * 4)        // 5403392

#define CHUNK16 128                          // rows per chunk
#define SPITCH  132                          // score pitch (128 + 4 pad)

// ---------------- Threefry-2x32 (standard 20-round, KAT-verified) ----------------
__device__ __forceinline__ uint32_t rotl32(uint32_t v, int d) {
  return (v << d) | (v >> (32 - d));
}

__device__ __forceinline__ void threefry2x32(uint32_t k0, uint32_t k1,
                                             uint32_t x0, uint32_t x1,
                                             uint32_t& y0, uint32_t& y1) {
  const uint32_t ks2 = k0 ^ k1 ^ 0x1BD11BDAu;
  const uint32_t ks[3] = {k0, k1, ks2};
  x0 += k0; x1 += k1;
  const int ra[4] = {13, 15, 26, 6};
  const int rb[4] = {17, 29, 16, 24};
#pragma unroll
  for (int g = 0; g < 5; ++g) {
    const int* r = (g & 1) ? rb : ra;
#pragma unroll
    for (int i = 0; i < 4; ++i) {
      x0 += x1;
      x1 = rotl32(x1, r[i]);
      x1 ^= x0;
    }
    x0 += ks[(g + 1) % 3];
    x1 += ks[(g + 2) % 3] + (uint32_t)(g + 1);
  }
  y0 = x0; y1 = x1;
}

__device__ __forceinline__ int sample_idx(int t) {
  uint32_t k2_0, k2_1, y0, y1;
  threefry2x32(0u, 42u, 0u, 1u, k2_0, k2_1);          // k2 = split(key(42))[1]
  threefry2x32(k2_0, k2_1, 0u, (uint32_t)t, y0, y1);  // partitionable draw
  return (int)((y0 ^ y1) & 2047u);
}

// t-parameterized draw with the (constant) split key hoisted by the caller.
__device__ __forceinline__ int sample_idx_k2(uint32_t k2_0, uint32_t k2_1, int t) {
  uint32_t y0, y1;
  threefry2x32(k2_0, k2_1, 0u, (uint32_t)t, y0, y1);
  return (int)((y0 ^ y1) & 2047u);
}

// ---- per-lane argmax over 32 regs, LOWEST slot on tie, dep-depth ~5 (r10) ----
__device__ __forceinline__ int argmax32_low(const float* __restrict__ vals,
                                            float& bv_out) {
  float t[16];
#pragma unroll
  for (int i = 0; i < 16; ++i) t[i] = fmaxf(vals[2 * i], vals[2 * i + 1]);
#pragma unroll
  for (int i = 0; i < 8; ++i) t[i] = fmaxf(t[2 * i], t[2 * i + 1]);
#pragma unroll
  for (int i = 0; i < 4; ++i) t[i] = fmaxf(t[2 * i], t[2 * i + 1]);
  float bv = fmaxf(fmaxf(t[0], t[1]), fmaxf(t[2], t[3]));
  uint32_t msk = 0u;
#pragma unroll
  for (int i = 0; i < 32; ++i)
    msk |= (vals[i] == bv) ? (1u << i) : 0u;
  bv_out = bv;
  return __ffs(msk) - 1;
}

// ---------------- top-38, ONE WAVE, serial (fallback paths only) ----------------
__device__ __forceinline__ void topk38_wave(const float* __restrict__ Mrow,
                                            int lane, int* __restrict__ mrow_out) {
  float vals[32];
#pragma unroll
  for (int i = 0; i < 32; ++i)
    vals[i] = Mrow[lane + 64 * i];

  for (int u = 0; u < NTOP; ++u) {
    float bv;
    int bslot = argmax32_low(vals, bv);
    float v = bv;
    int idx = lane + 64 * bslot;
#pragma unroll
    for (int off = 1; off < 64; off <<= 1) {   // tie -> lowest idx (lax.top_k)
      float v2 = __shfl_xor(v, off);
      int   i2 = __shfl_xor(idx, off);
      if (v2 > v || (v2 == v && i2 < idx)) { v = v2; idx = i2; }
    }
    if (lane == 0) mrow_out[u] = idx;
    if ((idx & 63) == lane) {
      int slot = idx >> 6;
#pragma unroll
      for (int i = 0; i < 32; ++i)
        if (i == slot) vals[i] = -1e38f;
    }
  }
}

// ---------------- r15/r16: block-parallel top-38 (512 threads, radix select) ------
__device__ __forceinline__ void topk38_block512(const float* __restrict__ Mrow,
                                                int tid,
                                                uint32_t* __restrict__ keys,   // [2048]
                                                uint32_t* __restrict__ whist,  // [2048] (also tie buf)
                                                uint32_t* __restrict__ hist,   // [256]
                                                int* __restrict__ sel,         // [40]
                                                int* __restrict__ cnts,        // [2]
                                                uint32_t* __restrict__ prsh,   // [2]
                                                int* __restrict__ spos,
                                                int* __restrict__ mtop_g, bool writeG) {
  int wv = tid >> 6;                          // 0..7
  for (int i = tid; i < L_; i += 512) {
    uint32_t u = __float_as_uint(Mrow[i]);
    keys[i] = (u & 0x80000000u) ? ~u : (u | 0x80000000u);
  }
  uint32_t prefix = 0u, remaining = NTOP;
  for (int level = 24; level >= 0; level -= 8) {
    for (int i = tid; i < 2048; i += 512) whist[i] = 0u;
    __syncthreads();
    uint32_t mask = (level == 24) ? 0u : (0xFFFFFFFFu << (level + 8));
    for (int i = tid; i < L_; i += 512) {
      uint32_t k = keys[i];
      if ((k & mask) == prefix)
        atomicAdd(&whist[wv * 256 + ((k >> level) & 255u)], 1u);
    }
    __syncthreads();
    if (tid < 256) {
      uint32_t s = 0u;
#pragma unroll
      for (int w2 = 0; w2 < 8; ++w2) s += whist[w2 * 256 + tid];
      hist[tid] = s;
    }
    __syncthreads();
    // r16: wave-0 parallel bucket select
    if (tid < 64) {
      uint32_t h0 = hist[4 * tid + 0];
      uint32_t h1 = hist[4 * tid + 1];
      uint32_t h2 = hist[4 * tid + 2];
      uint32_t h3 = hist[4 * tid + 3];
      uint32_t loc = h0 + h1 + h2 + h3;
      uint32_t T = loc;                      // inclusive suffix over lanes
#pragma unroll
      for (int off = 1; off < 64; off <<= 1) {
        uint32_t t2 = (uint32_t)__shfl_down((int)T, off);
        if (tid + off < 64) T += t2;
      }
      uint32_t S0 = T;                       // S(4t+i), non-increasing in b
      uint32_t S1 = S0 - h0;
      uint32_t S2 = S1 - h1;
      uint32_t S3 = S2 - h2;
      int cand = -1;
      uint32_t Ss = 0u, Hs = 0u;
      if (S3 >= remaining)      { cand = 4 * tid + 3; Ss = S3; Hs = h3; }
      else if (S2 >= remaining) { cand = 4 * tid + 2; Ss = S2; Hs = h2; }
      else if (S1 >= remaining) { cand = 4 * tid + 1; Ss = S1; Hs = h1; }
      else if (S0 >= remaining) { cand = 4 * tid + 0; Ss = S0; Hs = h0; }
#pragma unroll
      for (int off = 1; off < 64; off <<= 1) {
        int      oc = __shfl_xor(cand, off);
        uint32_t os = (uint32_t)__shfl_xor((int)Ss, off);
        uint32_t oh = (uint32_t)__shfl_xor((int)Hs, off);
        if (oc > cand) { cand = oc; Ss = os; Hs = oh; }
      }
      if (tid == 0) {
        prsh[0] = prefix | ((uint32_t)cand << level);
        prsh[1] = remaining - (Ss - Hs);     // == serial's remaining - cnt_above
      }
    }
    __syncthreads();
    prefix = prsh[0]; remaining = prsh[1];
  }
  uint32_t T = prefix;                        // 38th-largest key (exact)
  int need_ties = (int)remaining;             // 1..38; #keys==T to take
  uint32_t* tiebuf = whist;                   // reuse 8 KB
  if (tid == 0) { cnts[0] = 0; cnts[1] = 0; }
  __syncthreads();
  for (int i = tid; i < L_; i += 512) {
    uint32_t k = keys[i];
    if (k > T) {
      int s = atomicAdd(&cnts[0], 1);
      sel[s] = i;                             // nAbove = 38-need_ties <= 37
    } else if (k == T) {
      int s = atomicAdd(&cnts[1], 1);
      tiebuf[s] = (uint32_t)i;
    }
  }
  __syncthreads();
  int nAbove = cnts[0];
  int nTie = cnts[1];                         // >= need_ties (radix invariant)
  if (nTie == need_ties) {
    if (tid < need_ties) sel[nAbove + tid] = (int)tiebuf[tid];
  } else {                                    // rare: rank ties by index
    for (int i = tid; i < nTie; i += 512) {
      uint32_t my = tiebuf[i];
      int rank = 0;
      for (int j2 = 0; j2 < nTie; ++j2)
        rank += (tiebuf[j2] < my) ? 1 : 0;
      if (rank < need_ties) sel[nAbove + rank] = (int)my;
    }
  }
  __syncthreads();
  // canonical rank sort: (key desc, idx asc) -> exact lax.top_k order
  if (tid < NTOP) {
    int myidx = sel[tid];
    uint32_t myk = keys[myidx];
    int rank = 0;
#pragma unroll
    for (int j2 = 0; j2 < NTOP; ++j2) {
      int oidx = sel[j2];
      uint32_t ok = keys[oidx];
      rank += ((ok > myk) || (ok == myk && oidx < myidx)) ? 1 : 0;
    }
    spos[rank] = myidx;
    if (writeG) mtop_g[rank] = myidx;
  }
  __syncthreads();
}

// ---------------- k1: fused m + cumsum; r20 4-lane-subgroup dots ----------------
__global__ __launch_bounds__(256) void m_cumsum_kernel(const float* __restrict__ Q,
                                                       const float* __restrict__ K,
                                                       const float* __restrict__ V,
                                                       float* __restrict__ M,
                                                       float* __restrict__ out) {
  __shared__ uint16_t sidx[16][SAMPK];   // m path
  __shared__ float cs[8][32];            // cumsum path

  int tid = threadIdx.x;

  if (blockIdx.x < 64) {
    int bI = blockIdx.x;
    int bh = bI >> 1, dhalf = bI & 1;
    int h = bh & (H_ - 1), b = bh >> 3;
    int dl = tid & 31, c = tid >> 5;       // 8 chunks of 256 rows
    const int CH = L_ / 8;                 // 256
    int d = dhalf * 32 + dl;
    size_t base = ((size_t)b * L_ * H_ + h) * D_ + d;
    const size_t ls = (size_t)H_ * D_;     // 512
    float s = 0.f;
    for (int l = c * CH; l < (c + 1) * CH; ++l)
      s += V[base + (size_t)l * ls];
    cs[c][dl] = s;
    __syncthreads();
    float run = 0.f;
    for (int cc = 0; cc < c; ++cc) run += cs[cc][dl];
    for (int l = c * CH; l < (c + 1) * CH; ++l) {
      run += V[base + (size_t)l * ls];
      out[base + (size_t)l * ls] = run;
    }
    return;
  }

  // ---- m path (r20): 16 lanes per q = 4 subgroups x 4 lanes; subgroup sg owns
  // j in {sg, sg+4, ...}; each lane loads 4 contiguous float4 (64B) so the
  // 4-lane group still covers the full 256B K row (r9 coalescing preserved).
  // Butterfly per dot: 2 steps (offs 1,2) + one final 4-op cross-sg combine.
  int bI = blockIdx.x - 64;             // 0..4095
  int j8 = bI >> 3;                     // 0..511
  int bh = (bI & 7) + 8 * (j8 >> 7);    // blockIdx%8 == bh%8 -> same XCD
  int chunk = j8 & 127;                 // 128 chunks of 16 q per bh
  int grp = tid >> 4;                   // q index within chunk
  int l16 = tid & 15;                   // lane within q-group
  int sg = l16 >> 2, cc = l16 & 3;      // subgroup 0..3, lane-in-subgroup
  int q = chunk * 16 + grp;
  int h = bh & (H_ - 1), b = bh >> 3;

  {
    uint32_t k2_0, k2_1;
    threefry2x32(0u, 42u, 0u, 1u, k2_0, k2_1);   // constant; hoisted (r8)
    for (int s = tid; s < 16 * SAMPK; s += 256) {
      int ql = s / SAMPK, jj = s - ql * SAMPK;
      sidx[ql][jj] =
          (uint16_t)sample_idx_k2(k2_0, k2_1, (chunk * 16 + ql) * SAMPK + jj);
    }
  }
  __syncthreads();

  const float* Qrow = Q + (((size_t)b * L_ + q) * H_ + h) * D_ + 16 * cc;
  float4 q0 = *(const float4*)(Qrow + 0);
  float4 q1 = *(const float4*)(Qrow + 4);
  float4 q2 = *(const float4*)(Qrow + 8);
  float4 q3 = *(const float4*)(Qrow + 12);
  const float* Kbase = K + ((size_t)b * L_ * H_ + h) * D_ + 16 * cc;

  float mx = -1e30f, smv = 0.f;
  // all subgroups run exactly 5 iterations (38 = 4*9+2; strides align) -> no
  // trip-count divergence; shuffles (offs 1,2) stay within uniform subgroups.
  for (int j = sg; j < SAMPK; j += 8) {
    int r0 = (int)sidx[grp][j];
    const float* K0 = Kbase + (size_t)r0 * (H_ * D_);
    float4 a0 = *(const float4*)(K0 + 0);
    float4 a1 = *(const float4*)(K0 + 4);
    float4 a2 = *(const float4*)(K0 + 8);
    float4 a3 = *(const float4*)(K0 + 12);

    int jb = j + 4;
    bool has1 = jb < SAMPK;             // subgroup-uniform
    float4 b0, b1, b2, b3;
    if (has1) {
      int r1 = (int)sidx[grp][jb];
      const float* K1 = Kbase + (size_t)r1 * (H_ * D_);
      b0 = *(const float4*)(K1 + 0);
      b1 = *(const float4*)(K1 + 4);
      b2 = *(const float4*)(K1 + 8);
      b3 = *(const float4*)(K1 + 12);
    }

    float pa = (q0.x * a0.x + q0.y * a0.y + q0.z * a0.z + q0.w * a0.w)
             + (q1.x * a1.x + q1.y * a1.y + q1.z * a1.z + q1.w * a1.w)
             + (q2.x * a2.x + q2.y * a2.y + q2.z * a2.z + q2.w * a2.w)
             + (q3.x * a3.x + q3.y * a3.y + q3.z * a3.z + q3.w * a3.w);
    pa += __shfl_xor(pa, 1);
    pa += __shfl_xor(pa, 2);
    mx = fmaxf(mx, pa);
    smv += pa;

    if (has1) {
      float pb = (q0.x * b0.x + q0.y * b0.y + q0.z * b0.z + q0.w * b0.w)
               + (q1.x * b1.x + q1.y * b1.y + q1.z * b1.z + q1.w * b1.w)
               + (q2.x * b2.x + q2.y * b2.y + q2.z * b2.z + q2.w * b2.w)
               + (q3.x * b3.x + q3.y * b3.y + q3.z * b3.z + q3.w * b3.w);
      pb += __shfl_xor(pb, 1);
      pb += __shfl_xor(pb, 2);
      mx = fmaxf(mx, pb);
      smv += pb;
    }
  }
  // cross-subgroup combine (within the 16 lanes of q): max exact; sum reordered
  mx = fmaxf(mx, __shfl_xor(mx, 4));
  mx = fmaxf(mx, __shfl_xor(mx, 8));
  smv += __shfl_xor(smv, 4);
  smv += __shfl_xor(smv, 8);
  if (l16 == 0)
    M[(size_t)bh * L_ + q] = mx - smv * (1.0f / (float)L_);
}

// ---------------- k2: 16-chunk attn partials + parallel topk + V-in-sK (r19) ----
__global__ __launch_bounds__(512) void attn_split_tk_kernel(const float* __restrict__ Q,
                                                            const float* __restrict__ K,
                                                            const float* __restrict__ V,
                                                            const float* __restrict__ M,
                                                            int* __restrict__ mtop,
                                                            float* __restrict__ pmax,
                                                            float* __restrict__ psum,
                                                            float* __restrict__ ppv) {
  __shared__ float4 sK[CHUNK16 * 16];      // 32 KB, slot-swizzled (K in P2, V in P3)
  __shared__ float  sS[NTOP * SPITCH];     // 19.6 KB scores/probs (topk scratch alias)
  __shared__ float4 sQ[NTOP * 16];         // 9.5 KB
  __shared__ int    spos[NTOP];
  __shared__ int    sel[40];
  __shared__ int    cnts[2];
  __shared__ uint32_t prsh[2];

  int bI = blockIdx.x;
  int c = bI & 15;
  int bh = bI >> 4;
  int h = bh & (H_ - 1), b = bh >> 3;
  int kstart = c * CHUNK16;
  int tid = threadIdx.x;

  const float* Kb = K + ((size_t)b * L_ * H_ + h) * D_;
  const float* Vb = V + ((size_t)b * L_ * H_ + h) * D_;
  const float* Qb = Q + ((size_t)b * L_ * H_ + h) * D_;

  // ---- parallel topk (all 512 threads); scratch aliased into sS (dead here) ----
  {
    uint32_t* keys  = (uint32_t*)sS;          // [2048]  8 KB
    uint32_t* whist = (uint32_t*)sS + 2048;   // [2048]  8 KB (also tie buf)
    uint32_t* hist  = (uint32_t*)sS + 4096;   // [256]   1 KB   (total 17 KB <= 19.6)
    topk38_block512(M + (size_t)bh * L_, tid, keys, whist, hist, sel, cnts, prsh,
                    spos, mtop + bh * NTOP, c == 0);
  }

  int maxpos = 0;
  for (int u = 0; u < NTOP; ++u) maxpos = max(maxpos, spos[u]);
  if (maxpos < kstart) return;             // block-uniform (spos shared), after barrier

  // stage K chunk + Q top-38 rows (all 512 threads)
  for (int s = tid; s < CHUNK16 * 16; s += 512) {
    int row = s >> 4, f = s & 15;
    sK[row * 16 + (f ^ (row & 15))] =
        *(const float4*)(Kb + (size_t)(kstart + row) * (H_ * D_) + 4 * f);
  }
  for (int s = tid; s < NTOP * 16; s += 512) {
    int u = s >> 4, f = s & 15;
    sQ[s] = *(const float4*)(Qb + (size_t)spos[u] * (H_ * D_) + 4 * f);
  }
  __syncthreads();

  // ---- P2: scores (r4-verified form; K moved to kreg registers) ----
  {
    int k = tid & 127;            // row within chunk
    int ug = tid >> 7;            // 0..3, wave-uniform
    float4 kreg[16];
#pragma unroll
    for (int f = 0; f < 16; ++f)
      kreg[f] = sK[k * 16 + (f ^ (k & 15))];

    int u0 = ug * 10, u1 = min(NTOP, u0 + 10);
    for (int u = u0; u < u1; ++u) {
      int pos = spos[u];
      if (pos < kstart) continue;          // wave-uniform per u
      int kloc = pos - kstart;
      float dot = 0.f;
#pragma unroll
      for (int f = 0; f < 16; ++f) {
        float4 qf = sQ[u * 16 + f];        // broadcast read
        dot += kreg[f].x * qf.x + kreg[f].y * qf.y
             + kreg[f].z * qf.z + kreg[f].w * qf.w;
      }
      sS[u * SPITCH + k] = (k <= kloc) ? dot * 0.125f : -1e30f;
    }
  }
  __syncthreads();

  // ---- r19: stage V chunk into sK (K data dead after kreg loads) ----
  for (int s = tid; s < CHUNK16 * 16; s += 512) {
    int row = s >> 4, f = s & 15;
    sK[row * 16 + (f ^ (row & 15))] =
        *(const float4*)(Vb + (size_t)(kstart + row) * (H_ * D_) + 4 * f);
  }
  __syncthreads();

  // ---- P3: softmax + PV per wave (u stride 8), V from LDS, no more barriers ----
  int w = tid >> 6, lane = tid & 63;
  int kq = lane >> 4, dq = lane & 15;
  for (int u = w; u < NTOP; u += 8) {
    int pos = spos[u];
    if (pos < kstart) continue;
    int kcnt = min(CHUNK16, pos + 1 - kstart);

    float s0 = sS[u * SPITCH + lane];
    float s1 = sS[u * SPITCH + 64 + lane];
    float m = fmaxf(s0, s1);
#pragma unroll
    for (int off = 1; off < 64; off <<= 1)
      m = fmaxf(m, __shfl_xor(m, off));
    float p0 = expf(s0 - m), p1 = expf(s1 - m);
    sS[u * SPITCH + lane] = p0;            // wave-coherent write-back
    sS[u * SPITCH + 64 + lane] = p1;
    float sum = p0 + p1;
#pragma unroll
    for (int off = 1; off < 64; off <<= 1)
      sum += __shfl_xor(sum, off);

    float4 acc = make_float4(0.f, 0.f, 0.f, 0.f);
    for (int k0 = 0; k0 < kcnt; k0 += 4) {
      int kk = k0 + kq;
      if (kk < kcnt) {
        float p = sS[u * SPITCH + kk];     // 4 distinct addrs -> bcast
        float4 v4 = sK[kk * 16 + (dq ^ (kk & 15))];   // LDS, swizzle-matched
        acc.x += p * v4.x; acc.y += p * v4.y;
        acc.z += p * v4.z; acc.w += p * v4.w;
      }
    }
    acc.x += __shfl_xor(acc.x, 16); acc.y += __shfl_xor(acc.y, 16);
    acc.z += __shfl_xor(acc.z, 16); acc.w += __shfl_xor(acc.w, 16);
    acc.x += __shfl_xor(acc.x, 32); acc.y += __shfl_xor(acc.y, 32);
    acc.z += __shfl_xor(acc.z, 32); acc.w += __shfl_xor(acc.w, 32);

    int slot = (bh * NTOP + u) * 16 + c;
    if (lane < 16)
      *(float4*)(ppv + (size_t)slot * D_ + 4 * lane) = acc;
    if (lane == 0) { pmax[slot] = m; psum[slot] = sum; }
  }
}

// ---------------- k3: combine chunk partials, write out row ----------------
template <int NCHT>
__global__ __launch_bounds__(64) void attn_fin_kernel(const float* __restrict__ pmax,
                                                      const float* __restrict__ psum,
                                                      const float* __restrict__ ppv,
                                                      const int* __restrict__ mtop,
                                                      float* __restrict__ out) {
  const int CH = L_ / NCHT;
  int uu = blockIdx.x;            // 0..1215 == bh*NTOP + u
  int bh = uu / NTOP;
  int h = bh & (H_ - 1), b = bh >> 3;
  int pos = mtop[uu];
  if (pos < 0) pos = 0;
  if (pos > L_ - 1) pos = L_ - 1;
  int klen = pos + 1;
  int nch = (klen + CH - 1) / CH;
  int tid = threadIdx.x;          // == d

  int base = uu * NCHT;
  float gmax = -1e30f;
#pragma unroll
  for (int cc = 0; cc < NCHT; ++cc)
    if (cc < nch) gmax = fmaxf(gmax, pmax[base + cc]);

  float gsum = 0.f, acc = 0.f;
#pragma unroll
  for (int cc = 0; cc < NCHT; ++cc) {
    if (cc < nch) {
      float w0 = expf(pmax[base + cc] - gmax);
      gsum += psum[base + cc] * w0;
      acc += ppv[(size_t)(base + cc) * D_ + tid] * w0;
    }
  }
  out[(((size_t)b * L_ + pos) * H_ + h) * D_ + tid] = acc / gsum;
}

// ================= deep fallbacks (small-ws / zero-ws) =================
__global__ __launch_bounds__(256) void m_kernel(const float* __restrict__ Q,
                                                const float* __restrict__ K,
                                                float* __restrict__ M) {
  int bI = blockIdx.x;
  int j8 = bI >> 3;
  int bh = (bI & 7) + 8 * (j8 >> 7);
  int chunk = j8 & 127;
  int tid = threadIdx.x;
  int grp = tid >> 4, c = tid & 15;
  int q = chunk * 16 + grp;
  int h = bh & (H_ - 1), b = bh >> 3;

  __shared__ uint16_t sidx[16][SAMPK];
  for (int s = tid; s < 16 * SAMPK; s += 256) {
    int ql = s / SAMPK, jj = s - ql * SAMPK;
    sidx[ql][jj] = (uint16_t)sample_idx((chunk * 16 + ql) * SAMPK + jj);
  }
  __syncthreads();

  float4 qv = *(const float4*)(Q + (((size_t)b * L_ + q) * H_ + h) * D_ + 4 * c);
  const float* Kbase = K + ((size_t)b * L_ * H_ + h) * D_ + 4 * c;

  float mx = -1e30f, smv = 0.f;
  for (int j = 0; j < SAMPK; ++j) {
    int row = (int)sidx[grp][j];
    float4 kv = *(const float4*)(Kbase + (size_t)row * (H_ * D_));
    float part = qv.x * kv.x + qv.y * kv.y + qv.z * kv.z + qv.w * kv.w;
#pragma unroll
    for (int off = 1; off < 16; off <<= 1)
      part += __shfl_xor(part, off);
    mx = fmaxf(mx, part);
    smv += part;
  }
  if (c == 0)
    M[(size_t)bh * L_ + q] = mx - smv * (1.0f / (float)L_);
}

__global__ __launch_bounds__(1024) void cumsum_kernel(const float* __restrict__ V,
                                                      float* __restrict__ out) {
  int bI = blockIdx.x;
  int bh = bI >> 1, dhalf = bI & 1;
  int h = bh & (H_ - 1), b = bh >> 3;
  int tid = threadIdx.x;
  int dl = tid & 31, c = tid >> 5;
  int d = dhalf * 32 + dl;
  const int CH = L_ / 32;
  __shared__ float cs[32][32];
  size_t base = ((size_t)b * L_ * H_ + h) * D_ + d;
  const size_t ls = (size_t)H_ * D_;
  float s = 0.f;
  for (int l = c * CH; l < (c + 1) * CH; ++l)
    s += V[base + (size_t)l * ls];
  cs[c][dl] = s;
  __syncthreads();
  float run = 0.f;
  for (int cc = 0; cc < c; ++cc) run += cs[cc][dl];
  for (int l = c * CH; l < (c + 1) * CH; ++l) {
    run += V[base + (size_t)l * ls];
    out[base + (size_t)l * ls] = run;
  }
}

__global__ __launch_bounds__(64) void topk_reg_kernel(const float* __restrict__ M,
                                                      int* __restrict__ mtop) {
  int bh = blockIdx.x;
  topk38_wave(M + (size_t)bh * L_, threadIdx.x, mtop + bh * NTOP);
}

__global__ __launch_bounds__(256) void attn_kernel(const float* __restrict__ Q,
                                                   const float* __restrict__ K,
                                                   const float* __restrict__ V,
                                                   const int* __restrict__ mtop,
                                                   float* __restrict__ out) {
  int bI = blockIdx.x;
  int j = bI >> 3;
  int u = j % NTOP;
  int bh = (bI & 7) + 8 * (j / NTOP);
  int h = bh & (H_ - 1), b = bh >> 3;
  int tid = threadIdx.x;

  int pos = mtop[bh * NTOP + u];
  if (pos < 0) pos = 0;
  if (pos > L_ - 1) pos = L_ - 1;
  int klen = pos + 1;

  __shared__ float qs[D_];
  __shared__ float sc[L_];
  __shared__ float redv[256];
  __shared__ float4 part4[16][16];

  if (tid < D_)
    qs[tid] = Q[(((size_t)b * L_ + pos) * H_ + h) * D_ + tid];
  __syncthreads();

  int c16 = tid & 15, g = tid >> 4;
  float4 qreg = *(const float4*)(qs + 4 * c16);
  const float* Kbase = K + ((size_t)b * L_ * H_ + h) * D_ + 4 * c16;
  float lmax = -1e30f;
  for (int k = g; k < klen; k += 16) {
    float4 kv = *(const float4*)(Kbase + (size_t)k * (H_ * D_));
    float part = qreg.x * kv.x + qreg.y * kv.y + qreg.z * kv.z + qreg.w * kv.w;
#pragma unroll
    for (int off = 1; off < 16; off <<= 1)
      part += __shfl_xor(part, off);
    part *= 0.125f;
    if (c16 == 0) sc[k] = part;
    lmax = fmaxf(lmax, part);
  }
  redv[tid] = lmax;
  __syncthreads();
  for (int s = 128; s > 0; s >>= 1) {
    if (tid < s) redv[tid] = fmaxf(redv[tid], redv[tid + s]);
    __syncthreads();
  }
  float mx = redv[0];
  __syncthreads();

  float lsum = 0.f;
  for (int k = tid; k < klen; k += 256) {
    float p = expf(sc[k] - mx);
    sc[k] = p;
    lsum += p;
  }
  redv[tid] = lsum;
  __syncthreads();
  for (int s = 128; s > 0; s >>= 1) {
    if (tid < s) redv[tid] += redv[tid + s];
    __syncthreads();
  }
  float inv = 1.0f / redv[0];
  __syncthreads();

  float4 acc = make_float4(0.f, 0.f, 0.f, 0.f);
  const float* Vbase = V + ((size_t)b * L_ * H_ + h) * D_ + 4 * c16;
  for (int k = g; k < klen; k += 16) {
    float p = sc[k];
    float4 v4 = *(const float4*)(Vbase + (size_t)k * (H_ * D_));
    acc.x += p * v4.x; acc.y += p * v4.y; acc.z += p * v4.z; acc.w += p * v4.w;
  }
  part4[g][c16] = acc;
  __syncthreads();
#pragma unroll
  for (int s = 8; s > 0; s >>= 1) {
    if (g < s) {
      float4 o = part4[g + s][c16];
      float4 m = part4[g][c16];
      m.x += o.x; m.y += o.y; m.z += o.z; m.w += o.w;
      part4[g][c16] = m;
    }
    __syncthreads();
  }
  if (tid < 16) {
    float4 r = part4[0][tid];
    r.x *= inv; r.y *= inv; r.z *= inv; r.w *= inv;
    *(float4*)(out + (((size_t)b * L_ + pos) * H_ + h) * D_ + 4 * tid) = r;
  }
}

__global__ __launch_bounds__(256) void fused_kernel(const float* __restrict__ Q,
                                                    const float* __restrict__ K,
                                                    const float* __restrict__ V,
                                                    float* __restrict__ out) {
  int bh = blockIdx.x;
  int h = bh % H_, b = bh / H_;
  int tid = threadIdx.x;

  __shared__ float sm[L_];
  __shared__ float redv[256];
  __shared__ int   redi[256];
  __shared__ int   mtop_s[NTOP];
  __shared__ float qs[D_];
  __shared__ float part[4][D_];

  for (int q = tid; q < L_; q += 256) {
    const float4* q4 = (const float4*)(Q + (((size_t)b * L_ + q) * H_ + h) * D_);
    float4 qv[16];
#pragma unroll
    for (int i = 0; i < 16; ++i) qv[i] = q4[i];
    float mx = -1e30f, smv = 0.f;
    for (int j = 0; j < SAMPK; ++j) {
      int kk = sample_idx(q * SAMPK + j);
      const float4* k4 = (const float4*)(K + (((size_t)b * L_ + kk) * H_ + h) * D_);
      float dot = 0.f;
#pragma unroll
      for (int i = 0; i < 16; ++i) {
        float4 kv = k4[i];
        dot += qv[i].x * kv.x + qv[i].y * kv.y + qv[i].z * kv.z + qv[i].w * kv.w;
      }
      mx = fmaxf(mx, dot);
      smv += dot;
    }
    sm[q] = mx - smv * (1.0f / (float)L_);
  }
  __syncthreads();

  for (int u = 0; u < NTOP; ++u) {
    float bv = -1e38f; int bi = -1;
    for (int i = tid; i < L_; i += 256) {
      float v = sm[i];
      if (v > bv) { bv = v; bi = i; }
    }
    redv[tid] = bv; redi[tid] = bi;
    __syncthreads();
    for (int s = 128; s > 0; s >>= 1) {
      if (tid < s) {
        float v2 = redv[tid + s]; int i2 = redi[tid + s];
        if (v2 > redv[tid] ||
            (v2 == redv[tid] && i2 >= 0 && (redi[tid] < 0 || i2 < redi[tid]))) {
          redv[tid] = v2; redi[tid] = i2;
        }
      }
      __syncthreads();
    }
    if (tid == 0) {
      int sel2 = redi[0];
      if (sel2 < 0) sel2 = 0;
      mtop_s[u] = sel2;
      sm[sel2] = -1e38f;
    }
    __syncthreads();
  }

  for (int u = 0; u < NTOP; ++u) {
    int pos = mtop_s[u];
    if (pos < 0) pos = 0;
    if (pos > L_ - 1) pos = L_ - 1;
    int klen = pos + 1;

    __syncthreads();
    if (tid < D_)
      qs[tid] = Q[(((size_t)b * L_ + pos) * H_ + h) * D_ + tid];
    __syncthreads();

    float lmax = -1e30f;
    for (int k = tid; k < klen; k += 256) {
      const float4* k4 = (const float4*)(K + (((size_t)b * L_ + k) * H_ + h) * D_);
      float dot = 0.f;
#pragma unroll
      for (int i = 0; i < 16; ++i) {
        float4 kv = k4[i];
        dot += qs[4 * i] * kv.x + qs[4 * i + 1] * kv.y
             + qs[4 * i + 2] * kv.z + qs[4 * i + 3] * kv.w;
      }
      dot *= 0.125f;
      sm[k] = dot;
      lmax = fmaxf(lmax, dot);
    }
    redv[tid] = lmax;
    __syncthreads();
    for (int s = 128; s > 0; s >>= 1) {
      if (tid < s) redv[tid] = fmaxf(redv[tid], redv[tid + s]);
      __syncthreads();
    }
    float mx = redv[0];
    __syncthreads();

    float lsum = 0.f;
    for (int k = tid; k < klen; k += 256) {
      float p = expf(sm[k] - mx);
      sm[k] = p;
      lsum += p;
    }
    redv[tid] = lsum;
    __syncthreads();
    for (int s = 128; s > 0; s >>= 1) {
      if (tid < s) redv[tid] += redv[tid + s];
      __syncthreads();
    }
    float inv = 1.0f / redv[0];
    __syncthreads();

    int d = tid & 63, slice = tid >> 6;
    float acc = 0.f;
    for (int k = slice; k < klen; k += 4)
      acc += sm[k] * V[(((size_t)b * L_ + k) * H_ + h) * D_ + d];
    part[slice][d] = acc;
    __syncthreads();
    if (tid < D_) {
      float r = (part[0][tid] + part[1][tid]) + (part[2][tid] + part[3][tid]);
      out[(((size_t)b * L_ + pos) * H_ + h) * D_ + tid] = r * inv;
    }
  }
}

extern "C" void kernel_launch(void* const* d_in, const int* in_sizes, int n_in,
                              void* d_out, int out_size, void* d_ws, size_t ws_size,
                              hipStream_t stream) {
  const float* Q = (const float*)d_in[0];
  const float* K = (const float*)d_in[1];
  const float* V = (const float*)d_in[2];
  float* out = (float*)d_out;

  if (ws_size >= (size_t)WS16_TOTAL) {
    char* ws = (char*)d_ws;
    float* M    = (float*)(ws + WS_M_OFF);
    int*   mt   = (int*)(ws + WS_MTOP_OFF);
    float* pmax = (float*)(ws + WS16_PMAX);
    float* psum = (float*)(ws + WS16_PSUM);
    float* ppv  = (float*)(ws + WS16_PPV);

    m_cumsum_kernel<<<4160, 256, 0, stream>>>(Q, K, V, M, out);
    attn_split_tk_kernel<<<B_ * H_ * 16, 512, 0, stream>>>(Q, K, V, M, mt,
                                                           pmax, psum, ppv);
    attn_fin_kernel<16><<<B_ * H_ * NTOP, 64, 0, stream>>>(pmax, psum, ppv, mt, out);
  } else if (ws_size >= (size_t)WS_SMALL) {
    char* ws = (char*)d_ws;
    float* M  = (float*)(ws + WS_M_OFF);
    int*   mt = (int*)(ws + WS_MTOP_OFF);

    m_kernel<<<4096, 256, 0, stream>>>(Q, K, M);
    topk_reg_kernel<<<B_ * H_, 64, 0, stream>>>(M, mt);
    cumsum_kernel<<<B_ * H_ * 2, 1024, 0, stream>>>(V, out);
    attn_kernel<<<B_ * H_ * NTOP, 256, 0, stream>>>(Q, K, V, mt, out);
  } else {
    cumsum_kernel<<<B_ * H_ * 2, 1024, 0, stream>>>(V, out);
    fused_kernel<<<B_ * H_, 256, 0, stream>>>(Q, K, V, out);
  }
}

// Round 20
// 166.475 us; speedup vs baseline: 1.0632x; 1.0632x over previous
//
#include <hip/hip_runtime.h>
#include <hip/hip_bf16.h>
#include <math.h>

// Problem constants (B,L,H,D fixed by setup_inputs; S == L)
#define B_   4
#define L_   2048
#define H_   8
#define D_   64
#define NTOP 38          // int(5*ln(2048)) = 38
#define SAMPK 38

// Verified RNG (r10 PASS): JAX partitionable threefry WITH randint key-split.
// r5 lesson: NO per-block fence/atomic producer-consumer (~170us cost).
// r9/r20 lesson: the m-gather's 16-lane-cooperative form with 4-deep MLP is
//   empirically optimal (4 independent rows in flight); both thread-per-row
//   (r9) and 4-lane-subgroup (r20) restructures lost memory parallelism.
// r11 lesson: grid.sync/cooperative launch incompatible with this harness.
// r15/r16 (PASS): block-parallel radix topk + parallel bucket select.
// r19 (PASS, 167.9us BEST): V staged into sK after P2 (sK dead) -> P3 V-reads
//   from LDS. Final configuration.

// ---- d_ws layouts ----
#define WS_M_OFF    0                        // float  M[65536]     = 262144 B
#define WS_MTOP_OFF 262144                   // int    mtop[32*38]  =   4864 B
#define WS_SMALL    (WS_MTOP_OFF + 4864)     // 267008 B
// 16-chunk layout (5.4 MB, r3/r4-verified fit) — primary path:
#define NSLOT16     (B_ * H_ * NTOP * 16)    // 19456
#define WS16_PMAX   WS_SMALL
#define WS16_PSUM   (WS16_PMAX + NSLOT16 * 4)
#define WS16_PPV    (WS16_PSUM + NSLOT16 * 4)
#define WS16_TOTAL  (WS16_PPV + NSLOT16 * D_ * 4)        // 5403392

#define CHUNK16 128                          // rows per chunk
#define SPITCH  132                          // score pitch (128 + 4 pad)

// ---------------- Threefry-2x32 (standard 20-round, KAT-verified) ----------------
__device__ __forceinline__ uint32_t rotl32(uint32_t v, int d) {
  return (v << d) | (v >> (32 - d));
}

__device__ __forceinline__ void threefry2x32(uint32_t k0, uint32_t k1,
                                             uint32_t x0, uint32_t x1,
                                             uint32_t& y0, uint32_t& y1) {
  const uint32_t ks2 = k0 ^ k1 ^ 0x1BD11BDAu;
  const uint32_t ks[3] = {k0, k1, ks2};
  x0 += k0; x1 += k1;
  const int ra[4] = {13, 15, 26, 6};
  const int rb[4] = {17, 29, 16, 24};
#pragma unroll
  for (int g = 0; g < 5; ++g) {
    const int* r = (g & 1) ? rb : ra;
#pragma unroll
    for (int i = 0; i < 4; ++i) {
      x0 += x1;
      x1 = rotl32(x1, r[i]);
      x1 ^= x0;
    }
    x0 += ks[(g + 1) % 3];
    x1 += ks[(g + 2) % 3] + (uint32_t)(g + 1);
  }
  y0 = x0; y1 = x1;
}

__device__ __forceinline__ int sample_idx(int t) {
  uint32_t k2_0, k2_1, y0, y1;
  threefry2x32(0u, 42u, 0u, 1u, k2_0, k2_1);          // k2 = split(key(42))[1]
  threefry2x32(k2_0, k2_1, 0u, (uint32_t)t, y0, y1);  // partitionable draw
  return (int)((y0 ^ y1) & 2047u);
}

// t-parameterized draw with the (constant) split key hoisted by the caller.
__device__ __forceinline__ int sample_idx_k2(uint32_t k2_0, uint32_t k2_1, int t) {
  uint32_t y0, y1;
  threefry2x32(k2_0, k2_1, 0u, (uint32_t)t, y0, y1);
  return (int)((y0 ^ y1) & 2047u);
}

// ---- per-lane argmax over 32 regs, LOWEST slot on tie, dep-depth ~5 (r10) ----
__device__ __forceinline__ int argmax32_low(const float* __restrict__ vals,
                                            float& bv_out) {
  float t[16];
#pragma unroll
  for (int i = 0; i < 16; ++i) t[i] = fmaxf(vals[2 * i], vals[2 * i + 1]);
#pragma unroll
  for (int i = 0; i < 8; ++i) t[i] = fmaxf(t[2 * i], t[2 * i + 1]);
#pragma unroll
  for (int i = 0; i < 4; ++i) t[i] = fmaxf(t[2 * i], t[2 * i + 1]);
  float bv = fmaxf(fmaxf(t[0], t[1]), fmaxf(t[2], t[3]));
  uint32_t msk = 0u;
#pragma unroll
  for (int i = 0; i < 32; ++i)
    msk |= (vals[i] == bv) ? (1u << i) : 0u;
  bv_out = bv;
  return __ffs(msk) - 1;
}

// ---------------- top-38, ONE WAVE, serial (fallback paths only) ----------------
__device__ __forceinline__ void topk38_wave(const float* __restrict__ Mrow,
                                            int lane, int* __restrict__ mrow_out) {
  float vals[32];
#pragma unroll
  for (int i = 0; i < 32; ++i)
    vals[i] = Mrow[lane + 64 * i];

  for (int u = 0; u < NTOP; ++u) {
    float bv;
    int bslot = argmax32_low(vals, bv);
    float v = bv;
    int idx = lane + 64 * bslot;
#pragma unroll
    for (int off = 1; off < 64; off <<= 1) {   // tie -> lowest idx (lax.top_k)
      float v2 = __shfl_xor(v, off);
      int   i2 = __shfl_xor(idx, off);
      if (v2 > v || (v2 == v && i2 < idx)) { v = v2; idx = i2; }
    }
    if (lane == 0) mrow_out[u] = idx;
    if ((idx & 63) == lane) {
      int slot = idx >> 6;
#pragma unroll
      for (int i = 0; i < 32; ++i)
        if (i == slot) vals[i] = -1e38f;
    }
  }
}

// ---------------- r15/r16: block-parallel top-38 (512 threads, radix select) ------
// keys: monotonic u32 map of M. 4x8-bit MSB radix passes (per-wave sub-histograms)
// -> exact 38th-largest key T + tie rank; collect {key>T} + lowest-index ties;
// canonical all-pairs rank sort (key desc, idx asc) == EXACT lax.top_k order.
// r16: bucket select via wave-0 parallel suffix scan.
__device__ __forceinline__ void topk38_block512(const float* __restrict__ Mrow,
                                                int tid,
                                                uint32_t* __restrict__ keys,   // [2048]
                                                uint32_t* __restrict__ whist,  // [2048] (also tie buf)
                                                uint32_t* __restrict__ hist,   // [256]
                                                int* __restrict__ sel,         // [40]
                                                int* __restrict__ cnts,        // [2]
                                                uint32_t* __restrict__ prsh,   // [2]
                                                int* __restrict__ spos,
                                                int* __restrict__ mtop_g, bool writeG) {
  int wv = tid >> 6;                          // 0..7
  for (int i = tid; i < L_; i += 512) {
    uint32_t u = __float_as_uint(Mrow[i]);
    keys[i] = (u & 0x80000000u) ? ~u : (u | 0x80000000u);
  }
  uint32_t prefix = 0u, remaining = NTOP;
  for (int level = 24; level >= 0; level -= 8) {
    for (int i = tid; i < 2048; i += 512) whist[i] = 0u;
    __syncthreads();
    uint32_t mask = (level == 24) ? 0u : (0xFFFFFFFFu << (level + 8));
    for (int i = tid; i < L_; i += 512) {
      uint32_t k = keys[i];
      if ((k & mask) == prefix)
        atomicAdd(&whist[wv * 256 + ((k >> level) & 255u)], 1u);
    }
    __syncthreads();
    if (tid < 256) {
      uint32_t s = 0u;
#pragma unroll
      for (int w2 = 0; w2 < 8; ++w2) s += whist[w2 * 256 + tid];
      hist[tid] = s;
    }
    __syncthreads();
    // r16: wave-0 parallel bucket select
    if (tid < 64) {
      uint32_t h0 = hist[4 * tid + 0];
      uint32_t h1 = hist[4 * tid + 1];
      uint32_t h2 = hist[4 * tid + 2];
      uint32_t h3 = hist[4 * tid + 3];
      uint32_t loc = h0 + h1 + h2 + h3;
      uint32_t T = loc;                      // inclusive suffix over lanes
#pragma unroll
      for (int off = 1; off < 64; off <<= 1) {
        uint32_t t2 = (uint32_t)__shfl_down((int)T, off);
        if (tid + off < 64) T += t2;
      }
      uint32_t S0 = T;                       // S(4t+i), non-increasing in b
      uint32_t S1 = S0 - h0;
      uint32_t S2 = S1 - h1;
      uint32_t S3 = S2 - h2;
      int cand = -1;
      uint32_t Ss = 0u, Hs = 0u;
      if (S3 >= remaining)      { cand = 4 * tid + 3; Ss = S3; Hs = h3; }
      else if (S2 >= remaining) { cand = 4 * tid + 2; Ss = S2; Hs = h2; }
      else if (S1 >= remaining) { cand = 4 * tid + 1; Ss = S1; Hs = h1; }
      else if (S0 >= remaining) { cand = 4 * tid + 0; Ss = S0; Hs = h0; }
#pragma unroll
      for (int off = 1; off < 64; off <<= 1) {
        int      oc = __shfl_xor(cand, off);
        uint32_t os = (uint32_t)__shfl_xor((int)Ss, off);
        uint32_t oh = (uint32_t)__shfl_xor((int)Hs, off);
        if (oc > cand) { cand = oc; Ss = os; Hs = oh; }
      }
      if (tid == 0) {
        prsh[0] = prefix | ((uint32_t)cand << level);
        prsh[1] = remaining - (Ss - Hs);     // == serial's remaining - cnt_above
      }
    }
    __syncthreads();
    prefix = prsh[0]; remaining = prsh[1];
  }
  uint32_t T = prefix;                        // 38th-largest key (exact)
  int need_ties = (int)remaining;             // 1..38; #keys==T to take
  uint32_t* tiebuf = whist;                   // reuse 8 KB
  if (tid == 0) { cnts[0] = 0; cnts[1] = 0; }
  __syncthreads();
  for (int i = tid; i < L_; i += 512) {
    uint32_t k = keys[i];
    if (k > T) {
      int s = atomicAdd(&cnts[0], 1);
      sel[s] = i;                             // nAbove = 38-need_ties <= 37
    } else if (k == T) {
      int s = atomicAdd(&cnts[1], 1);
      tiebuf[s] = (uint32_t)i;
    }
  }
  __syncthreads();
  int nAbove = cnts[0];
  int nTie = cnts[1];                         // >= need_ties (radix invariant)
  if (nTie == need_ties) {
    if (tid < need_ties) sel[nAbove + tid] = (int)tiebuf[tid];
  } else {                                    // rare: rank ties by index
    for (int i = tid; i < nTie; i += 512) {
      uint32_t my = tiebuf[i];
      int rank = 0;
      for (int j2 = 0; j2 < nTie; ++j2)
        rank += (tiebuf[j2] < my) ? 1 : 0;
      if (rank < need_ties) sel[nAbove + rank] = (int)my;
    }
  }
  __syncthreads();
  // canonical rank sort: (key desc, idx asc) -> exact lax.top_k order
  if (tid < NTOP) {
    int myidx = sel[tid];
    uint32_t myk = keys[myidx];
    int rank = 0;
#pragma unroll
    for (int j2 = 0; j2 < NTOP; ++j2) {
      int oidx = sel[j2];
      uint32_t ok = keys[oidx];
      rank += ((ok > myk) || (ok == myk && oidx < myidx)) ? 1 : 0;
    }
    spos[rank] = myidx;
    if (writeG) mtop_g[rank] = myidx;
  }
  __syncthreads();
}

// ---------------- k1: fused m + cumsum (r10-verified form, 50us) ----------------
__global__ __launch_bounds__(256) void m_cumsum_kernel(const float* __restrict__ Q,
                                                       const float* __restrict__ K,
                                                       const float* __restrict__ V,
                                                       float* __restrict__ M,
                                                       float* __restrict__ out) {
  __shared__ uint16_t sidx[16][SAMPK];   // m path
  __shared__ float cs[8][32];            // cumsum path

  int tid = threadIdx.x;

  if (blockIdx.x < 64) {
    int bI = blockIdx.x;
    int bh = bI >> 1, dhalf = bI & 1;
    int h = bh & (H_ - 1), b = bh >> 3;
    int dl = tid & 31, c = tid >> 5;       // 8 chunks of 256 rows
    const int CH = L_ / 8;                 // 256
    int d = dhalf * 32 + dl;
    size_t base = ((size_t)b * L_ * H_ + h) * D_ + d;
    const size_t ls = (size_t)H_ * D_;     // 512
    float s = 0.f;
    for (int l = c * CH; l < (c + 1) * CH; ++l)
      s += V[base + (size_t)l * ls];
    cs[c][dl] = s;
    __syncthreads();
    float run = 0.f;
    for (int cc = 0; cc < c; ++cc) run += cs[cc][dl];
    for (int l = c * CH; l < (c + 1) * CH; ++l) {
      run += V[base + (size_t)l * ls];
      out[base + (size_t)l * ls] = run;
    }
    return;
  }

  // ---- m path (r10-verified: 16 lanes/q, 4-deep MLP gathers) ----
  int bI = blockIdx.x - 64;             // 0..4095
  int j8 = bI >> 3;                     // 0..511
  int bh = (bI & 7) + 8 * (j8 >> 7);    // blockIdx%8 == bh%8 -> same XCD
  int chunk = j8 & 127;                 // 128 chunks of 16 q per bh
  int grp = tid >> 4, c = tid & 15;     // 16 groups x 16 lanes
  int q = chunk * 16 + grp;
  int h = bh & (H_ - 1), b = bh >> 3;

  {
    uint32_t k2_0, k2_1;
    threefry2x32(0u, 42u, 0u, 1u, k2_0, k2_1);   // constant; hoisted (r8)
    for (int s = tid; s < 16 * SAMPK; s += 256) {
      int ql = s / SAMPK, jj = s - ql * SAMPK;
      sidx[ql][jj] =
          (uint16_t)sample_idx_k2(k2_0, k2_1, (chunk * 16 + ql) * SAMPK + jj);
    }
  }
  __syncthreads();

  float4 qv = *(const float4*)(Q + (((size_t)b * L_ + q) * H_ + h) * D_ + 4 * c);
  const float* Kbase = K + ((size_t)b * L_ * H_ + h) * D_ + 4 * c;

  float mx = -1e30f, smv = 0.f;
  int j = 0;
  for (; j + 4 <= SAMPK; j += 4) {      // 4-deep MLP on the K gathers
    int r0 = (int)sidx[grp][j];
    int r1 = (int)sidx[grp][j + 1];
    int r2 = (int)sidx[grp][j + 2];
    int r3 = (int)sidx[grp][j + 3];
    float4 k0 = *(const float4*)(Kbase + (size_t)r0 * (H_ * D_));
    float4 k1 = *(const float4*)(Kbase + (size_t)r1 * (H_ * D_));
    float4 k2 = *(const float4*)(Kbase + (size_t)r2 * (H_ * D_));
    float4 k3 = *(const float4*)(Kbase + (size_t)r3 * (H_ * D_));
    float p0 = qv.x * k0.x + qv.y * k0.y + qv.z * k0.z + qv.w * k0.w;
    float p1 = qv.x * k1.x + qv.y * k1.y + qv.z * k1.z + qv.w * k1.w;
    float p2 = qv.x * k2.x + qv.y * k2.y + qv.z * k2.z + qv.w * k2.w;
    float p3 = qv.x * k3.x + qv.y * k3.y + qv.z * k3.z + qv.w * k3.w;
#pragma unroll
    for (int off = 1; off < 16; off <<= 1) {
      p0 += __shfl_xor(p0, off);
      p1 += __shfl_xor(p1, off);
      p2 += __shfl_xor(p2, off);
      p3 += __shfl_xor(p3, off);
    }
    mx = fmaxf(mx, p0); smv += p0;
    mx = fmaxf(mx, p1); smv += p1;
    mx = fmaxf(mx, p2); smv += p2;
    mx = fmaxf(mx, p3); smv += p3;
  }
  for (; j < SAMPK; ++j) {
    int r0 = (int)sidx[grp][j];
    float4 k0 = *(const float4*)(Kbase + (size_t)r0 * (H_ * D_));
    float p0 = qv.x * k0.x + qv.y * k0.y + qv.z * k0.z + qv.w * k0.w;
#pragma unroll
    for (int off = 1; off < 16; off <<= 1)
      p0 += __shfl_xor(p0, off);
    mx = fmaxf(mx, p0); smv += p0;
  }
  if (c == 0)
    M[(size_t)bh * L_ + q] = mx - smv * (1.0f / (float)L_);
}

// ---------------- k2: 16-chunk attn partials + parallel topk + V-in-sK (r19) ----
__global__ __launch_bounds__(512) void attn_split_tk_kernel(const float* __restrict__ Q,
                                                            const float* __restrict__ K,
                                                            const float* __restrict__ V,
                                                            const float* __restrict__ M,
                                                            int* __restrict__ mtop,
                                                            float* __restrict__ pmax,
                                                            float* __restrict__ psum,
                                                            float* __restrict__ ppv) {
  __shared__ float4 sK[CHUNK16 * 16];      // 32 KB, slot-swizzled (K in P2, V in P3)
  __shared__ float  sS[NTOP * SPITCH];     // 19.6 KB scores/probs (topk scratch alias)
  __shared__ float4 sQ[NTOP * 16];         // 9.5 KB
  __shared__ int    spos[NTOP];
  __shared__ int    sel[40];
  __shared__ int    cnts[2];
  __shared__ uint32_t prsh[2];

  int bI = blockIdx.x;
  int c = bI & 15;
  int bh = bI >> 4;
  int h = bh & (H_ - 1), b = bh >> 3;
  int kstart = c * CHUNK16;
  int tid = threadIdx.x;

  const float* Kb = K + ((size_t)b * L_ * H_ + h) * D_;
  const float* Vb = V + ((size_t)b * L_ * H_ + h) * D_;
  const float* Qb = Q + ((size_t)b * L_ * H_ + h) * D_;

  // ---- parallel topk (all 512 threads); scratch aliased into sS (dead here) ----
  {
    uint32_t* keys  = (uint32_t*)sS;          // [2048]  8 KB
    uint32_t* whist = (uint32_t*)sS + 2048;   // [2048]  8 KB (also tie buf)
    uint32_t* hist  = (uint32_t*)sS + 4096;   // [256]   1 KB   (total 17 KB <= 19.6)
    topk38_block512(M + (size_t)bh * L_, tid, keys, whist, hist, sel, cnts, prsh,
                    spos, mtop + bh * NTOP, c == 0);
  }

  int maxpos = 0;
  for (int u = 0; u < NTOP; ++u) maxpos = max(maxpos, spos[u]);
  if (maxpos < kstart) return;             // block-uniform (spos shared), after barrier

  // stage K chunk + Q top-38 rows (all 512 threads)
  for (int s = tid; s < CHUNK16 * 16; s += 512) {
    int row = s >> 4, f = s & 15;
    sK[row * 16 + (f ^ (row & 15))] =
        *(const float4*)(Kb + (size_t)(kstart + row) * (H_ * D_) + 4 * f);
  }
  for (int s = tid; s < NTOP * 16; s += 512) {
    int u = s >> 4, f = s & 15;
    sQ[s] = *(const float4*)(Qb + (size_t)spos[u] * (H_ * D_) + 4 * f);
  }
  __syncthreads();

  // ---- P2: scores (r4-verified form; K moved to kreg registers) ----
  {
    int k = tid & 127;            // row within chunk
    int ug = tid >> 7;            // 0..3, wave-uniform
    float4 kreg[16];
#pragma unroll
    for (int f = 0; f < 16; ++f)
      kreg[f] = sK[k * 16 + (f ^ (k & 15))];

    int u0 = ug * 10, u1 = min(NTOP, u0 + 10);
    for (int u = u0; u < u1; ++u) {
      int pos = spos[u];
      if (pos < kstart) continue;          // wave-uniform per u
      int kloc = pos - kstart;
      float dot = 0.f;
#pragma unroll
      for (int f = 0; f < 16; ++f) {
        float4 qf = sQ[u * 16 + f];        // broadcast read
        dot += kreg[f].x * qf.x + kreg[f].y * qf.y
             + kreg[f].z * qf.z + kreg[f].w * qf.w;
      }
      sS[u * SPITCH + k] = (k <= kloc) ? dot * 0.125f : -1e30f;
    }
  }
  __syncthreads();

  // ---- r19: stage V chunk into sK (K data dead after kreg loads) ----
  for (int s = tid; s < CHUNK16 * 16; s += 512) {
    int row = s >> 4, f = s & 15;
    sK[row * 16 + (f ^ (row & 15))] =
        *(const float4*)(Vb + (size_t)(kstart + row) * (H_ * D_) + 4 * f);
  }
  __syncthreads();

  // ---- P3: softmax + PV per wave (u stride 8), V from LDS, no more barriers ----
  int w = tid >> 6, lane = tid & 63;
  int kq = lane >> 4, dq = lane & 15;
  for (int u = w; u < NTOP; u += 8) {
    int pos = spos[u];
    if (pos < kstart) continue;
    int kcnt = min(CHUNK16, pos + 1 - kstart);

    float s0 = sS[u * SPITCH + lane];
    float s1 = sS[u * SPITCH + 64 + lane];
    float m = fmaxf(s0, s1);
#pragma unroll
    for (int off = 1; off < 64; off <<= 1)
      m = fmaxf(m, __shfl_xor(m, off));
    float p0 = expf(s0 - m), p1 = expf(s1 - m);
    sS[u * SPITCH + lane] = p0;            // wave-coherent write-back
    sS[u * SPITCH + 64 + lane] = p1;
    float sum = p0 + p1;
#pragma unroll
    for (int off = 1; off < 64; off <<= 1)
      sum += __shfl_xor(sum, off);

    float4 acc = make_float4(0.f, 0.f, 0.f, 0.f);
    for (int k0 = 0; k0 < kcnt; k0 += 4) {
      int kk = k0 + kq;
      if (kk < kcnt) {
        float p = sS[u * SPITCH + kk];     // 4 distinct addrs -> bcast
        float4 v4 = sK[kk * 16 + (dq ^ (kk & 15))];   // LDS, swizzle-matched
        acc.x += p * v4.x; acc.y += p * v4.y;
        acc.z += p * v4.z; acc.w += p * v4.w;
      }
    }
    acc.x += __shfl_xor(acc.x, 16); acc.y += __shfl_xor(acc.y, 16);
    acc.z += __shfl_xor(acc.z, 16); acc.w += __shfl_xor(acc.w, 16);
    acc.x += __shfl_xor(acc.x, 32); acc.y += __shfl_xor(acc.y, 32);
    acc.z += __shfl_xor(acc.z, 32); acc.w += __shfl_xor(acc.w, 32);

    int slot = (bh * NTOP + u) * 16 + c;
    if (lane < 16)
      *(float4*)(ppv + (size_t)slot * D_ + 4 * lane) = acc;
    if (lane == 0) { pmax[slot] = m; psum[slot] = sum; }
  }
}

// ---------------- k3: combine chunk partials, write out row ----------------
template <int NCHT>
__global__ __launch_bounds__(64) void attn_fin_kernel(const float* __restrict__ pmax,
                                                      const float* __restrict__ psum,
                                                      const float* __restrict__ ppv,
                                                      const int* __restrict__ mtop,
                                                      float* __restrict__ out) {
  const int CH = L_ / NCHT;
  int uu = blockIdx.x;            // 0..1215 == bh*NTOP + u
  int bh = uu / NTOP;
  int h = bh & (H_ - 1), b = bh >> 3;
  int pos = mtop[uu];
  if (pos < 0) pos = 0;
  if (pos > L_ - 1) pos = L_ - 1;
  int klen = pos + 1;
  int nch = (klen + CH - 1) / CH;
  int tid = threadIdx.x;          // == d

  int base = uu * NCHT;
  float gmax = -1e30f;
#pragma unroll
  for (int cc = 0; cc < NCHT; ++cc)
    if (cc < nch) gmax = fmaxf(gmax, pmax[base + cc]);

  float gsum = 0.f, acc = 0.f;
#pragma unroll
  for (int cc = 0; cc < NCHT; ++cc) {
    if (cc < nch) {
      float w0 = expf(pmax[base + cc] - gmax);
      gsum += psum[base + cc] * w0;
      acc += ppv[(size_t)(base + cc) * D_ + tid] * w0;
    }
  }
  out[(((size_t)b * L_ + pos) * H_ + h) * D_ + tid] = acc / gsum;
}

// ================= deep fallbacks (small-ws / zero-ws) =================
__global__ __launch_bounds__(256) void m_kernel(const float* __restrict__ Q,
                                                const float* __restrict__ K,
                                                float* __restrict__ M) {
  int bI = blockIdx.x;
  int j8 = bI >> 3;
  int bh = (bI & 7) + 8 * (j8 >> 7);
  int chunk = j8 & 127;
  int tid = threadIdx.x;
  int grp = tid >> 4, c = tid & 15;
  int q = chunk * 16 + grp;
  int h = bh & (H_ - 1), b = bh >> 3;

  __shared__ uint16_t sidx[16][SAMPK];
  for (int s = tid; s < 16 * SAMPK; s += 256) {
    int ql = s / SAMPK, jj = s - ql * SAMPK;
    sidx[ql][jj] = (uint16_t)sample_idx((chunk * 16 + ql) * SAMPK + jj);
  }
  __syncthreads();

  float4 qv = *(const float4*)(Q + (((size_t)b * L_ + q) * H_ + h) * D_ + 4 * c);
  const float* Kbase = K + ((size_t)b * L_ * H_ + h) * D_ + 4 * c;

  float mx = -1e30f, smv = 0.f;
  for (int j = 0; j < SAMPK; ++j) {
    int row = (int)sidx[grp][j];
    float4 kv = *(const float4*)(Kbase + (size_t)row * (H_ * D_));
    float part = qv.x * kv.x + qv.y * kv.y + qv.z * kv.z + qv.w * kv.w;
#pragma unroll
    for (int off = 1; off < 16; off <<= 1)
      part += __shfl_xor(part, off);
    mx = fmaxf(mx, part);
    smv += part;
  }
  if (c == 0)
    M[(size_t)bh * L_ + q] = mx - smv * (1.0f / (float)L_);
}

__global__ __launch_bounds__(1024) void cumsum_kernel(const float* __restrict__ V,
                                                      float* __restrict__ out) {
  int bI = blockIdx.x;
  int bh = bI >> 1, dhalf = bI & 1;
  int h = bh & (H_ - 1), b = bh >> 3;
  int tid = threadIdx.x;
  int dl = tid & 31, c = tid >> 5;
  int d = dhalf * 32 + dl;
  const int CH = L_ / 32;
  __shared__ float cs[32][32];
  size_t base = ((size_t)b * L_ * H_ + h) * D_ + d;
  const size_t ls = (size_t)H_ * D_;
  float s = 0.f;
  for (int l = c * CH; l < (c + 1) * CH; ++l)
    s += V[base + (size_t)l * ls];
  cs[c][dl] = s;
  __syncthreads();
  float run = 0.f;
  for (int cc = 0; cc < c; ++cc) run += cs[cc][dl];
  for (int l = c * CH; l < (c + 1) * CH; ++l) {
    run += V[base + (size_t)l * ls];
    out[base + (size_t)l * ls] = run;
  }
}

__global__ __launch_bounds__(64) void topk_reg_kernel(const float* __restrict__ M,
                                                      int* __restrict__ mtop) {
  int bh = blockIdx.x;
  topk38_wave(M + (size_t)bh * L_, threadIdx.x, mtop + bh * NTOP);
}

__global__ __launch_bounds__(256) void attn_kernel(const float* __restrict__ Q,
                                                   const float* __restrict__ K,
                                                   const float* __restrict__ V,
                                                   const int* __restrict__ mtop,
                                                   float* __restrict__ out) {
  int bI = blockIdx.x;
  int j = bI >> 3;
  int u = j % NTOP;
  int bh = (bI & 7) + 8 * (j / NTOP);
  int h = bh & (H_ - 1), b = bh >> 3;
  int tid = threadIdx.x;

  int pos = mtop[bh * NTOP + u];
  if (pos < 0) pos = 0;
  if (pos > L_ - 1) pos = L_ - 1;
  int klen = pos + 1;

  __shared__ float qs[D_];
  __shared__ float sc[L_];
  __shared__ float redv[256];
  __shared__ float4 part4[16][16];

  if (tid < D_)
    qs[tid] = Q[(((size_t)b * L_ + pos) * H_ + h) * D_ + tid];
  __syncthreads();

  int c16 = tid & 15, g = tid >> 4;
  float4 qreg = *(const float4*)(qs + 4 * c16);
  const float* Kbase = K + ((size_t)b * L_ * H_ + h) * D_ + 4 * c16;
  float lmax = -1e30f;
  for (int k = g; k < klen; k += 16) {
    float4 kv = *(const float4*)(Kbase + (size_t)k * (H_ * D_));
    float part = qreg.x * kv.x + qreg.y * kv.y + qreg.z * kv.z + qreg.w * kv.w;
#pragma unroll
    for (int off = 1; off < 16; off <<= 1)
      part += __shfl_xor(part, off);
    part *= 0.125f;
    if (c16 == 0) sc[k] = part;
    lmax = fmaxf(lmax, part);
  }
  redv[tid] = lmax;
  __syncthreads();
  for (int s = 128; s > 0; s >>= 1) {
    if (tid < s) redv[tid] = fmaxf(redv[tid], redv[tid + s]);
    __syncthreads();
  }
  float mx = redv[0];
  __syncthreads();

  float lsum = 0.f;
  for (int k = tid; k < klen; k += 256) {
    float p = expf(sc[k] - mx);
    sc[k] = p;
    lsum += p;
  }
  redv[tid] = lsum;
  __syncthreads();
  for (int s = 128; s > 0; s >>= 1) {
    if (tid < s) redv[tid] += redv[tid + s];
    __syncthreads();
  }
  float inv = 1.0f / redv[0];
  __syncthreads();

  float4 acc = make_float4(0.f, 0.f, 0.f, 0.f);
  const float* Vbase = V + ((size_t)b * L_ * H_ + h) * D_ + 4 * c16;
  for (int k = g; k < klen; k += 16) {
    float p = sc[k];
    float4 v4 = *(const float4*)(Vbase + (size_t)k * (H_ * D_));
    acc.x += p * v4.x; acc.y += p * v4.y; acc.z += p * v4.z; acc.w += p * v4.w;
  }
  part4[g][c16] = acc;
  __syncthreads();
#pragma unroll
  for (int s = 8; s > 0; s >>= 1) {
    if (g < s) {
      float4 o = part4[g + s][c16];
      float4 m = part4[g][c16];
      m.x += o.x; m.y += o.y; m.z += o.z; m.w += o.w;
      part4[g][c16] = m;
    }
    __syncthreads();
  }
  if (tid < 16) {
    float4 r = part4[0][tid];
    r.x *= inv; r.y *= inv; r.z *= inv; r.w *= inv;
    *(float4*)(out + (((size_t)b * L_ + pos) * H_ + h) * D_ + 4 * tid) = r;
  }
}

__global__ __launch_bounds__(256) void fused_kernel(const float* __restrict__ Q,
                                                    const float* __restrict__ K,
                                                    const float* __restrict__ V,
                                                    float* __restrict__ out) {
  int bh = blockIdx.x;
  int h = bh % H_, b = bh / H_;
  int tid = threadIdx.x;

  __shared__ float sm[L_];
  __shared__ float redv[256];
  __shared__ int   redi[256];
  __shared__ int   mtop_s[NTOP];
  __shared__ float qs[D_];
  __shared__ float part[4][D_];

  for (int q = tid; q < L_; q += 256) {
    const float4* q4 = (const float4*)(Q + (((size_t)b * L_ + q) * H_ + h) * D_);
    float4 qv[16];
#pragma unroll
    for (int i = 0; i < 16; ++i) qv[i] = q4[i];
    float mx = -1e30f, smv = 0.f;
    for (int j = 0; j < SAMPK; ++j) {
      int kk = sample_idx(q * SAMPK + j);
      const float4* k4 = (const float4*)(K + (((size_t)b * L_ + kk) * H_ + h) * D_);
      float dot = 0.f;
#pragma unroll
      for (int i = 0; i < 16; ++i) {
        float4 kv = k4[i];
        dot += qv[i].x * kv.x + qv[i].y * kv.y + qv[i].z * kv.z + qv[i].w * kv.w;
      }
      mx = fmaxf(mx, dot);
      smv += dot;
    }
    sm[q] = mx - smv * (1.0f / (float)L_);
  }
  __syncthreads();

  for (int u = 0; u < NTOP; ++u) {
    float bv = -1e38f; int bi = -1;
    for (int i = tid; i < L_; i += 256) {
      float v = sm[i];
      if (v > bv) { bv = v; bi = i; }
    }
    redv[tid] = bv; redi[tid] = bi;
    __syncthreads();
    for (int s = 128; s > 0; s >>= 1) {
      if (tid < s) {
        float v2 = redv[tid + s]; int i2 = redi[tid + s];
        if (v2 > redv[tid] ||
            (v2 == redv[tid] && i2 >= 0 && (redi[tid] < 0 || i2 < redi[tid]))) {
          redv[tid] = v2; redi[tid] = i2;
        }
      }
      __syncthreads();
    }
    if (tid == 0) {
      int sel2 = redi[0];
      if (sel2 < 0) sel2 = 0;
      mtop_s[u] = sel2;
      sm[sel2] = -1e38f;
    }
    __syncthreads();
  }

  for (int u = 0; u < NTOP; ++u) {
    int pos = mtop_s[u];
    if (pos < 0) pos = 0;
    if (pos > L_ - 1) pos = L_ - 1;
    int klen = pos + 1;

    __syncthreads();
    if (tid < D_)
      qs[tid] = Q[(((size_t)b * L_ + pos) * H_ + h) * D_ + tid];
    __syncthreads();

    float lmax = -1e30f;
    for (int k = tid; k < klen; k += 256) {
      const float4* k4 = (const float4*)(K + (((size_t)b * L_ + k) * H_ + h) * D_);
      float dot = 0.f;
#pragma unroll
      for (int i = 0; i < 16; ++i) {
        float4 kv = k4[i];
        dot += qs[4 * i] * kv.x + qs[4 * i + 1] * kv.y
             + qs[4 * i + 2] * kv.z + qs[4 * i + 3] * kv.w;
      }
      dot *= 0.125f;
      sm[k] = dot;
      lmax = fmaxf(lmax, dot);
    }
    redv[tid] = lmax;
    __syncthreads();
    for (int s = 128; s > 0; s >>= 1) {
      if (tid < s) redv[tid] = fmaxf(redv[tid], redv[tid + s]);
      __syncthreads();
    }
    float mx = redv[0];
    __syncthreads();

    float lsum = 0.f;
    for (int k = tid; k < klen; k += 256) {
      float p = expf(sm[k] - mx);
      sm[k] = p;
      lsum += p;
    }
    redv[tid] = lsum;
    __syncthreads();
    for (int s = 128; s > 0; s >>= 1) {
      if (tid < s) redv[tid] += redv[tid + s];
      __syncthreads();
    }
    float inv = 1.0f / redv[0];
    __syncthreads();

    int d = tid & 63, slice = tid >> 6;
    float acc = 0.f;
    for (int k = slice; k < klen; k += 4)
      acc += sm[k] * V[(((size_t)b * L_ + k) * H_ + h) * D_ + d];
    part[slice][d] = acc;
    __syncthreads();
    if (tid < D_) {
      float r = (part[0][tid] + part[1][tid]) + (part[2][tid] + part[3][tid]);
      out[(((size_t)b * L_ + pos) * H_ + h) * D_ + tid] = r * inv;
    }
  }
}

extern "C" void kernel_launch(void* const* d_in, const int* in_sizes, int n_in,
                              void* d_out, int out_size, void* d_ws, size_t ws_size,
                              hipStream_t stream) {
  const float* Q = (const float*)d_in[0];
  const float* K = (const float*)d_in[1];
  const float* V = (const float*)d_in[2];
  float* out = (float*)d_out;

  if (ws_size >= (size_t)WS16_TOTAL) {
    char* ws = (char*)d_ws;
    float* M    = (float*)(ws + WS_M_OFF);
    int*   mt   = (int*)(ws + WS_MTOP_OFF);
    float* pmax = (float*)(ws + WS16_PMAX);
    float* psum = (float*)(ws + WS16_PSUM);
    float* ppv  = (float*)(ws + WS16_PPV);

    m_cumsum_kernel<<<4160, 256, 0, stream>>>(Q, K, V, M, out);
    attn_split_tk_kernel<<<B_ * H_ * 16, 512, 0, stream>>>(Q, K, V, M, mt,
                                                           pmax, psum, ppv);
    attn_fin_kernel<16><<<B_ * H_ * NTOP, 64, 0, stream>>>(pmax, psum, ppv, mt, out);
  } else if (ws_size >= (size_t)WS_SMALL) {
    char* ws = (char*)d_ws;
    float* M  = (float*)(ws + WS_M_OFF);
    int*   mt = (int*)(ws + WS_MTOP_OFF);

    m_kernel<<<4096, 256, 0, stream>>>(Q, K, M);
    topk_reg_kernel<<<B_ * H_, 64, 0, stream>>>(M, mt);
    cumsum_kernel<<<B_ * H_ * 2, 1024, 0, stream>>>(V, out);
    attn_kernel<<<B_ * H_ * NTOP, 256, 0, stream>>>(Q, K, V, mt, out);
  } else {
    cumsum_kernel<<<B_ * H_ * 2, 1024, 0, stream>>>(V, out);
    fused_kernel<<<B_ * H_, 256, 0, stream>>>(Q, K, V, out);
  }
}